// Round 1
// baseline (501.903 us; speedup 1.0000x reference)
//
#include <hip/hip_runtime.h>
#include <math.h>

#define N 8192
#define F 8
#define ROWS_PER_WAVE 4
#define WAVES_PER_BLOCK 4
#define ROWS_PER_BLOCK (ROWS_PER_WAVE * WAVES_PER_BLOCK)  // 16
#define JCHUNK 2048

// Kernel 1: msg[i][f] = sum_j max(A[i][j], fid_adj[i][j]) * X[j][f]
// fid_adj = 1 iff (cos(x_i,x_j))^2 >= 0.9 and i != j.
// Since A ~ U[0,1), max(a, 1) == 1 exactly -> adj = cond ? 1.0f : a.
__global__ __launch_bounds__(256) void msg_pass_kernel(
    const float* __restrict__ A, const float* __restrict__ X,
    float* __restrict__ msg) {
  const int lane = threadIdx.x & 63;
  const int wave = threadIdx.x >> 6;
  const int i0 = blockIdx.x * ROWS_PER_BLOCK + wave * ROWS_PER_WAVE;
  const int jbase = blockIdx.y * JCHUNK;

  // Load this wave's 4 source rows (wave-uniform addresses -> broadcast).
  float xi[ROWS_PER_WAVE][F];
  float inv_i[ROWS_PER_WAVE];
#pragma unroll
  for (int r = 0; r < ROWS_PER_WAVE; ++r) {
    const float4* xr = (const float4*)(X + (size_t)(i0 + r) * F);
    float4 lo = xr[0], hi = xr[1];
    xi[r][0] = lo.x; xi[r][1] = lo.y; xi[r][2] = lo.z; xi[r][3] = lo.w;
    xi[r][4] = hi.x; xi[r][5] = hi.y; xi[r][6] = hi.z; xi[r][7] = hi.w;
    float ss = 0.f;
#pragma unroll
    for (int f = 0; f < F; ++f) ss += xi[r][f] * xi[r][f];
    inv_i[r] = 1.0f / (sqrtf(ss) + 1e-12f);
  }

  float acc[ROWS_PER_WAVE][F];
#pragma unroll
  for (int r = 0; r < ROWS_PER_WAVE; ++r)
#pragma unroll
    for (int f = 0; f < F; ++f) acc[r][f] = 0.f;

#pragma unroll 2
  for (int it = 0; it < JCHUNK / 64; ++it) {
    const int j = jbase + it * 64 + lane;
    const float4* xjp = (const float4*)(X + (size_t)j * F);
    float4 lo = xjp[0], hi = xjp[1];
    float xj[F] = {lo.x, lo.y, lo.z, lo.w, hi.x, hi.y, hi.z, hi.w};
    float ssj = 0.f;
#pragma unroll
    for (int f = 0; f < F; ++f) ssj += xj[f] * xj[f];
    const float inv_j = 1.0f / (sqrtf(ssj) + 1e-12f);

#pragma unroll
    for (int r = 0; r < ROWS_PER_WAVE; ++r) {
      float dot = 0.f;
#pragma unroll
      for (int f = 0; f < F; ++f) dot += xi[r][f] * xj[f];
      const float c = dot * inv_i[r] * inv_j;
      const float fid = c * c;
      const float a = A[(size_t)(i0 + r) * N + j];
      const bool sel = (fid >= 0.9f) && (j != i0 + r);
      const float adj = sel ? 1.0f : a;
#pragma unroll
      for (int f = 0; f < F; ++f) acc[r][f] += adj * xj[f];
    }
  }

  // Wave-level butterfly reduce; lane (r*8+f) owns that output's atomic.
#pragma unroll
  for (int r = 0; r < ROWS_PER_WAVE; ++r) {
#pragma unroll
    for (int f = 0; f < F; ++f) {
      float v = acc[r][f];
#pragma unroll
      for (int off = 1; off < 64; off <<= 1) v += __shfl_xor(v, off, 64);
      if (lane == r * F + f) atomicAdd(msg + (size_t)(i0 + r) * F + f, v);
    }
  }
}

__device__ __forceinline__ float sigmoidf_(float z) {
  return 1.0f / (1.0f + expf(-z));
}

// Kernel 2: per-node MLP chain. Weights are (fan_in, fan_out) row-major.
__global__ __launch_bounds__(256) void mlp_kernel(
    const float* __restrict__ msg,
    const float* __restrict__ W_fm, const float* __restrict__ b_fm,
    const float* __restrict__ W_c1, const float* __restrict__ b_c1,
    const float* __restrict__ W_p1, const float* __restrict__ b_p1,
    const float* __restrict__ W_c2, const float* __restrict__ b_c2,
    const float* __restrict__ W_p2, const float* __restrict__ b_p2,
    const float* __restrict__ W_c3, const float* __restrict__ b_c3,
    const float* __restrict__ W_h, const float* __restrict__ b_h,
    float* __restrict__ out) {
  const int i = blockIdx.x * blockDim.x + threadIdx.x;
  if (i >= N) return;

  float h0[8];
#pragma unroll
  for (int f = 0; f < 8; ++f) h0[f] = msg[(size_t)i * 8 + f];

  float h1[16];
#pragma unroll
  for (int o = 0; o < 16; ++o) {
    float z = b_fm[o];
#pragma unroll
    for (int k = 0; k < 8; ++k) z += h0[k] * W_fm[k * 16 + o];
    h1[o] = tanhf(z);
  }
  float h2[16];
#pragma unroll
  for (int o = 0; o < 16; ++o) {
    float z = b_c1[o];
#pragma unroll
    for (int k = 0; k < 16; ++k) z += h1[k] * W_c1[k * 16 + o];
    h2[o] = tanhf(z);
  }
  float h3[12];
#pragma unroll
  for (int o = 0; o < 12; ++o) {
    float z = b_p1[o];
#pragma unroll
    for (int k = 0; k < 16; ++k) z += h2[k] * W_p1[k * 12 + o];
    h3[o] = tanhf(z);
  }
  float h4[8];
#pragma unroll
  for (int o = 0; o < 8; ++o) {
    float z = b_c2[o];
#pragma unroll
    for (int k = 0; k < 12; ++k) z += h3[k] * W_c2[k * 8 + o];
    h4[o] = tanhf(z);
  }
  float h5[4];
#pragma unroll
  for (int o = 0; o < 4; ++o) {
    float z = b_p2[o];
#pragma unroll
    for (int k = 0; k < 8; ++k) z += h4[k] * W_p2[k * 4 + o];
    h5[o] = tanhf(z);
  }
  float h6[4];
#pragma unroll
  for (int o = 0; o < 4; ++o) {
    float z = b_c3[o];
#pragma unroll
    for (int k = 0; k < 4; ++k) z += h5[k] * W_c3[k * 4 + o];
    h6[o] = tanhf(z);
  }
  float z = b_h[0];
#pragma unroll
  for (int k = 0; k < 4; ++k) z += h6[k] * W_h[k];
  out[i] = sigmoidf_(z);
}

extern "C" void kernel_launch(void* const* d_in, const int* in_sizes, int n_in,
                              void* d_out, int out_size, void* d_ws,
                              size_t ws_size, hipStream_t stream) {
  const float* A = (const float*)d_in[0];
  const float* X = (const float*)d_in[1];
  const float* W_fm = (const float*)d_in[2];
  const float* b_fm = (const float*)d_in[3];
  const float* W_c1 = (const float*)d_in[4];
  const float* b_c1 = (const float*)d_in[5];
  const float* W_p1 = (const float*)d_in[6];
  const float* b_p1 = (const float*)d_in[7];
  const float* W_c2 = (const float*)d_in[8];
  const float* b_c2 = (const float*)d_in[9];
  const float* W_p2 = (const float*)d_in[10];
  const float* b_p2 = (const float*)d_in[11];
  const float* W_c3 = (const float*)d_in[12];
  const float* b_c3 = (const float*)d_in[13];
  const float* W_h = (const float*)d_in[14];
  const float* b_h = (const float*)d_in[15];
  float* out = (float*)d_out;
  float* msg = (float*)d_ws;  // (N, F) fp32 intermediate = 256 KiB

  // ws is poisoned 0xAA before every call; atomics need zeros.
  hipMemsetAsync(msg, 0, (size_t)N * F * sizeof(float), stream);

  dim3 grid(N / ROWS_PER_BLOCK, N / JCHUNK);
  msg_pass_kernel<<<grid, dim3(256), 0, stream>>>(A, X, msg);

  mlp_kernel<<<dim3(N / 256), dim3(256), 0, stream>>>(
      msg, W_fm, b_fm, W_c1, b_c1, W_p1, b_p1, W_c2, b_c2, W_p2, b_p2, W_c3,
      b_c3, W_h, b_h, out);
}

// Round 2
// 470.519 us; speedup vs baseline: 1.0667x; 1.0667x over previous
//
#include <hip/hip_runtime.h>
#include <math.h>

#define N 8192
#define F 8
#define RPW 4                 // rows per wave
#define WPB 4                 // waves per block
#define RPB (RPW * WPB)       // 16 rows per block
#define JSPLIT 4
#define JCHUNK (N / JSPLIT)   // 2048 columns per block
// per iteration a wave covers 256 j (4 per lane); JCHUNK/256 = 8 iterations

// Pre-kernel: xn[i] = X[i] / (||X[i]|| + 1e-12), s[i] = ||X[i]|| + 1e-12.
// X is reconstructed in the hot loop as xn*s (rel err ~1e-7, harmless).
__global__ __launch_bounds__(256) void normalize_kernel(
    const float* __restrict__ X, float* __restrict__ xn,
    float* __restrict__ s) {
  const int i = blockIdx.x * 256 + threadIdx.x;
  if (i >= N) return;
  const float4* xp = (const float4*)(X + (size_t)i * F);
  float4 lo = xp[0], hi = xp[1];
  float ss = lo.x * lo.x + lo.y * lo.y + lo.z * lo.z + lo.w * lo.w +
             hi.x * hi.x + hi.y * hi.y + hi.z * hi.z + hi.w * hi.w;
  const float nrm = sqrtf(ss) + 1e-12f;
  const float inv = 1.0f / nrm;
  float4* xo = (float4*)(xn + (size_t)i * F);
  xo[0] = make_float4(lo.x * inv, lo.y * inv, lo.z * inv, lo.w * inv);
  xo[1] = make_float4(hi.x * inv, hi.y * inv, hi.z * inv, hi.w * inv);
  s[i] = nrm;
}

// msg[i][f] = sum_j max(A[i][j], fid_adj[i][j]) * X[j][f]
// fid_adj = 1 iff (xn_i . xn_j)^2 >= 0.9 and i != j.
// A ~ U[0,1) so max(a,1)==1 exactly -> adj = sel ? 1.0f : a.
__global__ __launch_bounds__(256) void msg_pass_kernel(
    const float* __restrict__ A, const float* __restrict__ xn,
    const float* __restrict__ s, float* __restrict__ msg) {
  const int lane = threadIdx.x & 63;
  const int wave = threadIdx.x >> 6;
  const int i0 = blockIdx.x * RPB + wave * RPW;
  const int jbase = blockIdx.y * JCHUNK;

  // This wave's 4 normalized source rows (wave-uniform -> broadcast loads).
  float xi[RPW][F];
#pragma unroll
  for (int r = 0; r < RPW; ++r) {
    const float4* xr = (const float4*)(xn + (size_t)(i0 + r) * F);
    float4 lo = xr[0], hi = xr[1];
    xi[r][0] = lo.x; xi[r][1] = lo.y; xi[r][2] = lo.z; xi[r][3] = lo.w;
    xi[r][4] = hi.x; xi[r][5] = hi.y; xi[r][6] = hi.z; xi[r][7] = hi.w;
  }

  float acc[RPW][F];
#pragma unroll
  for (int r = 0; r < RPW; ++r)
#pragma unroll
    for (int f = 0; f < F; ++f) acc[r][f] = 0.f;

  for (int it = 0; it < JCHUNK / 256; ++it) {
    const int j0 = jbase + it * 256 + lane * 4;

    // A: 4 rows x float4 (16 B/lane each) -> 4 KB/wave in flight.
    float4 a[RPW];
#pragma unroll
    for (int r = 0; r < RPW; ++r)
      a[r] = *(const float4*)(A + (size_t)(i0 + r) * N + j0);

#pragma unroll
    for (int k = 0; k < 4; ++k) {
      const int j = j0 + k;
      const float4* xjp = (const float4*)(xn + (size_t)j * F);
      float4 lo = xjp[0], hi = xjp[1];
      const float xj[F] = {lo.x, lo.y, lo.z, lo.w, hi.x, hi.y, hi.z, hi.w};
      const float sj = s[j];
#pragma unroll
      for (int r = 0; r < RPW; ++r) {
        float dot = 0.f;
#pragma unroll
        for (int f = 0; f < F; ++f) dot += xi[r][f] * xj[f];
        const bool sel = (dot * dot >= 0.9f) && (j != i0 + r);
        const float av = (k == 0) ? a[r].x : (k == 1) ? a[r].y
                       : (k == 2) ? a[r].z : a[r].w;
        const float coef = (sel ? 1.0f : av) * sj;  // X[j] = xn[j]*s[j]
#pragma unroll
        for (int f = 0; f < F; ++f) acc[r][f] += coef * xj[f];
      }
    }
  }

  // Wave butterfly reduce; lane (r*8+f) owns that output's atomic.
#pragma unroll
  for (int r = 0; r < RPW; ++r) {
#pragma unroll
    for (int f = 0; f < F; ++f) {
      float v = acc[r][f];
#pragma unroll
      for (int off = 1; off < 64; off <<= 1) v += __shfl_xor(v, off, 64);
      if (lane == r * F + f) atomicAdd(msg + (size_t)(i0 + r) * F + f, v);
    }
  }
}

__device__ __forceinline__ float sigmoidf_(float z) {
  return 1.0f / (1.0f + expf(-z));
}

// Per-node MLP chain. Weights are (fan_in, fan_out) row-major.
__global__ __launch_bounds__(256) void mlp_kernel(
    const float* __restrict__ msg,
    const float* __restrict__ W_fm, const float* __restrict__ b_fm,
    const float* __restrict__ W_c1, const float* __restrict__ b_c1,
    const float* __restrict__ W_p1, const float* __restrict__ b_p1,
    const float* __restrict__ W_c2, const float* __restrict__ b_c2,
    const float* __restrict__ W_p2, const float* __restrict__ b_p2,
    const float* __restrict__ W_c3, const float* __restrict__ b_c3,
    const float* __restrict__ W_h, const float* __restrict__ b_h,
    float* __restrict__ out) {
  const int i = blockIdx.x * blockDim.x + threadIdx.x;
  if (i >= N) return;

  float h0[8];
#pragma unroll
  for (int f = 0; f < 8; ++f) h0[f] = msg[(size_t)i * 8 + f];

  float h1[16];
#pragma unroll
  for (int o = 0; o < 16; ++o) {
    float z = b_fm[o];
#pragma unroll
    for (int k = 0; k < 8; ++k) z += h0[k] * W_fm[k * 16 + o];
    h1[o] = tanhf(z);
  }
  float h2[16];
#pragma unroll
  for (int o = 0; o < 16; ++o) {
    float z = b_c1[o];
#pragma unroll
    for (int k = 0; k < 16; ++k) z += h1[k] * W_c1[k * 16 + o];
    h2[o] = tanhf(z);
  }
  float h3[12];
#pragma unroll
  for (int o = 0; o < 12; ++o) {
    float z = b_p1[o];
#pragma unroll
    for (int k = 0; k < 16; ++k) z += h2[k] * W_p1[k * 12 + o];
    h3[o] = tanhf(z);
  }
  float h4[8];
#pragma unroll
  for (int o = 0; o < 8; ++o) {
    float z = b_c2[o];
#pragma unroll
    for (int k = 0; k < 12; ++k) z += h3[k] * W_c2[k * 8 + o];
    h4[o] = tanhf(z);
  }
  float h5[4];
#pragma unroll
  for (int o = 0; o < 4; ++o) {
    float z = b_p2[o];
#pragma unroll
    for (int k = 0; k < 8; ++k) z += h4[k] * W_p2[k * 4 + o];
    h5[o] = tanhf(z);
  }
  float h6[4];
#pragma unroll
  for (int o = 0; o < 4; ++o) {
    float z = b_c3[o];
#pragma unroll
    for (int k = 0; k < 4; ++k) z += h5[k] * W_c3[k * 4 + o];
    h6[o] = tanhf(z);
  }
  float z = b_h[0];
#pragma unroll
  for (int k = 0; k < 4; ++k) z += h6[k] * W_h[k];
  out[i] = sigmoidf_(z);
}

extern "C" void kernel_launch(void* const* d_in, const int* in_sizes, int n_in,
                              void* d_out, int out_size, void* d_ws,
                              size_t ws_size, hipStream_t stream) {
  const float* A = (const float*)d_in[0];
  const float* X = (const float*)d_in[1];
  const float* W_fm = (const float*)d_in[2];
  const float* b_fm = (const float*)d_in[3];
  const float* W_c1 = (const float*)d_in[4];
  const float* b_c1 = (const float*)d_in[5];
  const float* W_p1 = (const float*)d_in[6];
  const float* b_p1 = (const float*)d_in[7];
  const float* W_c2 = (const float*)d_in[8];
  const float* b_c2 = (const float*)d_in[9];
  const float* W_p2 = (const float*)d_in[10];
  const float* b_p2 = (const float*)d_in[11];
  const float* W_c3 = (const float*)d_in[12];
  const float* b_c3 = (const float*)d_in[13];
  const float* W_h = (const float*)d_in[14];
  const float* b_h = (const float*)d_in[15];
  float* out = (float*)d_out;

  float* msg = (float*)d_ws;                     // (N,8) fp32, 256 KiB
  float* xn = msg + (size_t)N * F;               // (N,8) fp32, 256 KiB
  float* sn = xn + (size_t)N * F;                // (N,)  fp32,  32 KiB

  // ws is poisoned 0xAA before every call; atomics need zeros.
  hipMemsetAsync(msg, 0, (size_t)N * F * sizeof(float), stream);

  normalize_kernel<<<dim3(N / 256), dim3(256), 0, stream>>>(X, xn, sn);

  dim3 grid(N / RPB, JSPLIT);
  msg_pass_kernel<<<grid, dim3(256), 0, stream>>>(A, xn, sn, msg);

  mlp_kernel<<<dim3(N / 256), dim3(256), 0, stream>>>(
      msg, W_fm, b_fm, W_c1, b_c1, W_p1, b_p1, W_c2, b_c2, W_p2, b_p2, W_c3,
      b_c3, W_h, b_h, out);
}